// Round 12
// baseline (348.174 us; speedup 1.0000x reference)
//
#include <hip/hip_runtime.h>
#include <hip/hip_cooperative_groups.h>

namespace cg = cooperative_groups;

typedef float  f32x4 __attribute__((ext_vector_type(4)));
typedef short  s16x8 __attribute__((ext_vector_type(8)));
typedef _Float16 h2 __attribute__((ext_vector_type(2)));
typedef unsigned short u16;
typedef u16 u16x4 __attribute__((ext_vector_type(4)));

#define N_DIMS 1024
#define N_OSC  352
#define BATCH  4096
#define EPSV   1e-6f
#define INV2PI 0.15915494309189535f

#define NX4 1048576   // 4096*1024/4
#define NW4 90112     // 352*1024/4 (per weight matrix)
#define NCONV (NX4 + 2*NW4)   // 1,228,800 u16x4 items

__device__ __forceinline__ u16 f2bf(float f){
  unsigned u = __builtin_bit_cast(unsigned, f);
  u += 0x7FFFu + ((u >> 16) & 1u);   // round-to-nearest-even
  return (u16)(u >> 16);
}
__device__ __forceinline__ float bf2f(unsigned h){
  return __builtin_bit_cast(float, h << 16);
}

__device__ __forceinline__ void gload16(const u16* g, u16* l){
  __builtin_amdgcn_global_load_lds(
      (const __attribute__((address_space(1))) unsigned int*)(g),
      (__attribute__((address_space(3))) unsigned int*)(l), 16, 0, 0);
}

// ---- iter helpers ----
__device__ __forceinline__ int ibc(h2 v){ return __builtin_bit_cast(int, v); }
__device__ __forceinline__ h2  hbc(int v){ return __builtin_bit_cast(h2, v); }

__device__ __forceinline__ h2 rowsum16(h2 x){
  int v = ibc(x);
  v = ibc(hbc(v) + hbc(__builtin_amdgcn_mov_dpp(v, 0x121, 0xF, 0xF, true))); // row_ror:1
  v = ibc(hbc(v) + hbc(__builtin_amdgcn_mov_dpp(v, 0x122, 0xF, 0xF, true))); // row_ror:2
  v = ibc(hbc(v) + hbc(__builtin_amdgcn_mov_dpp(v, 0x124, 0xF, 0xF, true))); // row_ror:4
  v = ibc(hbc(v) + hbc(__builtin_amdgcn_mov_dpp(v, 0x128, 0xF, 0xF, true))); // row_ror:8
  return hbc(v);
}

__device__ __forceinline__ void updp(h2& s, h2& c, h2 cA, h2 sA, h2 GS, h2 GC){
  h2 e  = c*GS - s*GC;        // eps (radians), |e| <= 0.02
  h2 s1 = s*cA + c*sA;
  h2 c1 = c*cA - s*sA;
  s = s1 + c1*e;
  c = c1 - s1*e;
}

__device__ __forceinline__ h2 splat2(_Float16 v){ h2 r; r[0]=v; r[1]=v; return r; }

// ================= fused cooperative kernel =================
// Phase 1: f32->bf16 convert (grid-stride).  grid.sync
// Phase 2: GEMM C[4096][704] (R11 structure: 64^3 tiles, 4 waves, dbuf LDS,
//          global_load_lds, T2 swizzle, XCD-bijective 704=8x88).  grid.sync
// Phase 3: blocks < 256 run the 32-step phase iteration (R11 v2).
__global__ __launch_bounds__(256, 3) void fused_k(
    const f32x4* __restrict__ x, const f32x4* __restrict__ wp, const f32x4* __restrict__ wa,
    u16* __restrict__ xb, u16* __restrict__ wb, u16* __restrict__ phase0,
    float* __restrict__ amp){
  __shared__ u16 lds[2][8192];
  const int tid = threadIdx.x;
  const int bid = blockIdx.x;
  cg::grid_group grid = cg::this_grid();

  // ---------- phase 1: convert ----------
  {
    u16x4* xb4 = (u16x4*)xb;
    u16x4* wb4 = (u16x4*)wb;
    for (int i = bid*256 + tid; i < NCONV; i += 704*256){
      f32x4 v; u16x4* dst;
      if (i < NX4) { v = x[i]; dst = xb4 + i; }
      else {
        int j = i - NX4;
        v = (j < NW4) ? wp[j] : wa[j - NW4];
        dst = wb4 + j;
      }
      u16x4 r;
      r[0]=f2bf(v[0]); r[1]=f2bf(v[1]); r[2]=f2bf(v[2]); r[3]=f2bf(v[3]);
      *dst = r;
    }
  }
  __threadfence();
  grid.sync();

  // ---------- phase 2: gemm ----------
  {
    const int l = tid & 63;
    const int w = tid >> 6;

    const int xcd = bid & 7;
    const int r   = bid >> 3;
    const int mt  = xcd * 8 + r / 11;
    const int nt  = r % 11;
    const int m0  = mt * 64;
    const int n0  = nt * 64;

    const int srow = w*16 + (l >> 3);
    const int scol = (((l & 7) ^ (l >> 3)) * 8);
    const u16* ga = xb + (size_t)(m0 + srow) * N_DIMS + scol;
    const u16* gb = wb + (size_t)(n0 + srow) * N_DIMS + scol;

    #define STAGE(b, kt) { \
      const u16* gA = ga + (kt)*64; \
      const u16* gB = gb + (kt)*64; \
      gload16(gA,            &lds[b][w*1024]); \
      gload16(gA + 8*N_DIMS, &lds[b][w*1024 + 512]); \
      gload16(gB,            &lds[b][4096 + w*1024]); \
      gload16(gB + 8*N_DIMS, &lds[b][4096 + w*1024 + 512]); }

    const int rl = l & 15;
    const int q0 = l >> 4;
    const int sx = l & 7;
    const int wr = w >> 1, wc = w & 1;

    f32x4 acc[2][2] = {};
    STAGE(0, 0)
    __syncthreads();

    for (int kt = 0; kt < 16; kt++){
      const int cb = kt & 1;
      if (kt < 15) STAGE(cb^1, kt+1)
      s16x8 a[2][2], b[2][2];
      #pragma unroll
      for (int mi = 0; mi < 2; mi++)
      #pragma unroll
      for (int ks = 0; ks < 2; ks++){
        int off = (wr*32 + mi*16 + rl)*64 + (((ks*4 + q0) ^ sx) * 8);
        a[mi][ks] = *(const s16x8*)&lds[cb][off];
      }
      #pragma unroll
      for (int nj = 0; nj < 2; nj++)
      #pragma unroll
      for (int ks = 0; ks < 2; ks++){
        int off = 4096 + (wc*32 + nj*16 + rl)*64 + (((ks*4 + q0) ^ sx) * 8);
        b[nj][ks] = *(const s16x8*)&lds[cb][off];
      }
      #pragma unroll
      for (int ks = 0; ks < 2; ks++)
      #pragma unroll
      for (int mi = 0; mi < 2; mi++)
      #pragma unroll
      for (int nj = 0; nj < 2; nj++)
        acc[mi][nj] = __builtin_amdgcn_mfma_f32_16x16x32_bf16(a[mi][ks], b[nj][ks], acc[mi][nj], 0,0,0);
      __syncthreads();
    }
    #undef STAGE

    // C/D layout: col = lane&15, row = (lane>>4)*4 + reg
    #pragma unroll
    for (int mi = 0; mi < 2; mi++)
    #pragma unroll
    for (int nj = 0; nj < 2; nj++){
      const int n = n0 + wc*32 + nj*16 + rl;
      #pragma unroll
      for (int rg = 0; rg < 4; rg++){
        const int m = m0 + wr*32 + mi*16 + q0*4 + rg;
        float v = acc[mi][nj][rg];
        if (n < N_OSC) { float t = v * INV2PI; t -= floorf(t); phase0[(size_t)m*N_OSC + n] = f2bf(t); }
        else           { amp[(size_t)m*N_OSC + (n - N_OSC)] = fmaxf(fabsf(v), EPSV); }
      }
    }
  }
  __threadfence();
  grid.sync();

  // ---------- phase 3: iteration (blocks 0..255) ----------
  if (bid < 256){
    const int l   = tid & 63;
    const int g   = l & 15;
    const int row = bid*16 + (tid>>6)*4 + (l>>4);
    const size_t rb = (size_t)row * N_OSC;

    const h2 cAd = splat2((_Float16)0.99211470f), sAd = splat2((_Float16)0.12533323f);
    const h2 cAt = splat2((_Float16)0.92977649f), sAt = splat2((_Float16)0.36812455f);
    const h2 cAg = splat2((_Float16)-0.80901699f), sAg = splat2((_Float16)0.58778525f);
    const h2 kd = splat2((_Float16)6.25e-4f);    // DT*COUPLING/32
    const h2 kt = splat2((_Float16)3.125e-4f);   // /64
    const h2 kg = splat2((_Float16)7.8125e-5f);  // /256

    h2 sD, cD, sT[2], cT[2], sG[8], cG[8];
    {
      const u16* pr = phase0 + rb;
      unsigned dw = *(const unsigned*)(pr + 2*g);
      uint2 tw    = *(const uint2*)(pr + 32 + 4*g);
      uint4 g0w   = *(const uint4*)(pr + 96 + 16*g);
      uint4 g1w   = *(const uint4*)(pr + 96 + 16*g + 8);
      #define SC2(dS, dC, i, p0, p1) { \
        dS[i][0] = (_Float16)__builtin_amdgcn_sinf(p0); \
        dS[i][1] = (_Float16)__builtin_amdgcn_sinf(p1); \
        dC[i][0] = (_Float16)__builtin_amdgcn_cosf(p0); \
        dC[i][1] = (_Float16)__builtin_amdgcn_cosf(p1); }
      {
        float d0 = bf2f(dw & 0xFFFFu), d1 = bf2f(dw >> 16);
        sD[0] = (_Float16)__builtin_amdgcn_sinf(d0);
        sD[1] = (_Float16)__builtin_amdgcn_sinf(d1);
        cD[0] = (_Float16)__builtin_amdgcn_cosf(d0);
        cD[1] = (_Float16)__builtin_amdgcn_cosf(d1);
      }
      SC2(sT, cT, 0, bf2f(tw.x & 0xFFFFu), bf2f(tw.x >> 16))
      SC2(sT, cT, 1, bf2f(tw.y & 0xFFFFu), bf2f(tw.y >> 16))
      SC2(sG, cG, 0, bf2f(g0w.x & 0xFFFFu), bf2f(g0w.x >> 16))
      SC2(sG, cG, 1, bf2f(g0w.y & 0xFFFFu), bf2f(g0w.y >> 16))
      SC2(sG, cG, 2, bf2f(g0w.z & 0xFFFFu), bf2f(g0w.z >> 16))
      SC2(sG, cG, 3, bf2f(g0w.w & 0xFFFFu), bf2f(g0w.w >> 16))
      SC2(sG, cG, 4, bf2f(g1w.x & 0xFFFFu), bf2f(g1w.x >> 16))
      SC2(sG, cG, 5, bf2f(g1w.y & 0xFFFFu), bf2f(g1w.y >> 16))
      SC2(sG, cG, 6, bf2f(g1w.z & 0xFFFFu), bf2f(g1w.z >> 16))
      SC2(sG, cG, 7, bf2f(g1w.w & 0xFFFFu), bf2f(g1w.w >> 16))
      #undef SC2
    }

    h2 PD, PT, PG;
    #define REDUCE { \
      h2 pd; pd[0] = sD[0]+sD[1]; pd[1] = cD[0]+cD[1]; \
      h2 ts = sT[0]+sT[1], tc = cT[0]+cT[1]; \
      h2 pt; pt[0] = ts[0]+ts[1]; pt[1] = tc[0]+tc[1]; \
      h2 gs = ((sG[0]+sG[1])+(sG[2]+sG[3]))+((sG[4]+sG[5])+(sG[6]+sG[7])); \
      h2 gc = ((cG[0]+cG[1])+(cG[2]+cG[3]))+((cG[4]+cG[5])+(cG[6]+cG[7])); \
      h2 pg; pg[0] = gs[0]+gs[1]; pg[1] = gc[0]+gc[1]; \
      PD = rowsum16(pd); PT = rowsum16(pt); PG = rowsum16(pg); }

    REDUCE

    float Pth = 1.f, Pga = 1.f, mPth = 1.f, mPga = 1.f;
    for (int t = 0; t < 32; t++){
      h2 gd = PD * kd, gt = PT * kt, gg = PG * kg;
      h2 GSd = splat2(gd[0]), GCd = splat2(gd[1]);
      h2 GSt = splat2(gt[0]), GCt = splat2(gt[1]);
      h2 GSg = splat2(gg[0]), GCg = splat2(gg[1]);
      updp(sD, cD, cAd, sAd, GSd, GCd);
      updp(sT[0], cT[0], cAt, sAt, GSt, GCt);
      updp(sT[1], cT[1], cAt, sAt, GSt, GCt);
      #pragma unroll
      for (int i = 0; i < 8; i++) updp(sG[i], cG[i], cAg, sAg, GSg, GCg);
      REDUCE
      float Sd = (float)PD[0], Cd = (float)PD[1];
      float St = (float)PT[0], Ct = (float)PT[1];
      float ft = 1.f + 0.003f * Cd * __builtin_amdgcn_rsqf(Cd*Cd + Sd*Sd);
      float fg = 1.f + 0.003f * Ct * __builtin_amdgcn_rsqf(Ct*Ct + St*St);
      Pth *= ft; mPth = fminf(mPth, Pth);
      Pga *= fg; mPga = fminf(mPga, Pga);
    }
    #undef REDUCE

    const float cth = EPSV * Pth / mPth;
    const float cga = EPSV * Pga / mPga;
    {
      float4 a = *(const float4*)(amp + rb + 32 + 4*g);
      a.x = fmaxf(a.x*Pth, cth); a.y = fmaxf(a.y*Pth, cth);
      a.z = fmaxf(a.z*Pth, cth); a.w = fmaxf(a.w*Pth, cth);
      *(float4*)(amp + rb + 32 + 4*g) = a;
    }
    #pragma unroll
    for (int i = 0; i < 4; i++){
      float4 a = *(const float4*)(amp + rb + 96 + 16*g + 4*i);
      a.x = fmaxf(a.x*Pga, cga); a.y = fmaxf(a.y*Pga, cga);
      a.z = fmaxf(a.z*Pga, cga); a.w = fmaxf(a.w*Pga, cga);
      *(float4*)(amp + rb + 96 + 16*g + 4*i) = a;
    }
  }
}

// ---------------- launch ----------------
extern "C" void kernel_launch(void* const* d_in, const int* in_sizes, int n_in,
                              void* d_out, int out_size, void* d_ws, size_t ws_size,
                              hipStream_t stream){
  const f32x4* x  = (const f32x4*)d_in[0];
  const f32x4* wp = (const f32x4*)d_in[1];
  const f32x4* wa = (const f32x4*)d_in[2];
  float* out = (float*)d_out;
  char* ws = (char*)d_ws;
  u16* xb  = (u16*)(ws);                    // 8,388,608 B
  u16* wb  = (u16*)(ws + 8388608);          // 1,441,792 B
  u16* phase0 = (u16*)(ws + 9830400);       // 2,883,584 B (bf16)

  void* args[] = {(void*)&x, (void*)&wp, (void*)&wa,
                  (void*)&xb, (void*)&wb, (void*)&phase0, (void*)&out};
  hipLaunchCooperativeKernel((void*)fused_k, dim3(704), dim3(256), args, 0, stream);
}

// Round 13
// 157.831 us; speedup vs baseline: 2.2060x; 2.2060x over previous
//
#include <hip/hip_runtime.h>

typedef float  f32x4 __attribute__((ext_vector_type(4)));
typedef short  s16x8 __attribute__((ext_vector_type(8)));
typedef _Float16 h2 __attribute__((ext_vector_type(2)));
typedef unsigned short u16;
typedef u16 u16x4 __attribute__((ext_vector_type(4)));

#define N_DIMS 1024
#define N_OSC  352
#define BATCH  4096
#define EPSV   1e-6f
#define INV2PI 0.15915494309189535f

__device__ __forceinline__ u16 f2bf(float f){
  unsigned u = __builtin_bit_cast(unsigned, f);
  u += 0x7FFFu + ((u >> 16) & 1u);   // round-to-nearest-even
  return (u16)(u >> 16);
}
__device__ __forceinline__ float bf2f(unsigned h){
  return __builtin_bit_cast(float, h << 16);
}

#define NX4 1048576   // 4096*1024/4
#define NW4 90112     // 352*1024/4 (per weight matrix)

// ---------------- dispatch 1: convert f32 -> bf16 (+ zero strip counters) ----------------
__global__ __launch_bounds__(256) void convert_k(const f32x4* __restrict__ x,
    const f32x4* __restrict__ wp, const f32x4* __restrict__ wa,
    u16x4* __restrict__ xb, u16x4* __restrict__ wb, unsigned* __restrict__ cnt){
  int i = blockIdx.x * 256 + threadIdx.x;
  if (blockIdx.x == 0 && threadIdx.x < 64) cnt[threadIdx.x] = 0;
  f32x4 v; u16x4* dst;
  if (i < NX4) { v = x[i]; dst = xb + i; }
  else {
    int j = i - NX4;
    v = (j < NW4) ? wp[j] : wa[j - NW4];
    dst = wb + j;
  }
  u16x4 r;
  r[0]=f2bf(v[0]); r[1]=f2bf(v[1]); r[2]=f2bf(v[2]); r[3]=f2bf(v[3]);
  *dst = r;
}

// ---------------- dispatch 2: fused GEMM + per-strip iteration ----------------
// GEMM (R11 structure): BM=BN=BK=64, 4 waves, dbuf LDS 32 KB, global_load_lds,
// T2 swizzle via inverse-swizzled source, XCD-bijective 704 = 8 x 88.
// The 11 blocks of strip mt all live on ONE XCD -> same-L2 producer/consumer.
// After tile write: fence + atomicAdd(cnt[mt]); wave w (g = nt + 11*w < 16)
// spins until cnt[mt]==11, fences, then runs the v2 iter for rows mt*64+g*4..+3.
__device__ __forceinline__ void gload16(const u16* g, u16* l){
  __builtin_amdgcn_global_load_lds(
      (const __attribute__((address_space(1))) unsigned int*)(g),
      (__attribute__((address_space(3))) unsigned int*)(l), 16, 0, 0);
}

// ---- iter helpers (v2) ----
__device__ __forceinline__ int ibc(h2 v){ return __builtin_bit_cast(int, v); }
__device__ __forceinline__ h2  hbc(int v){ return __builtin_bit_cast(h2, v); }

__device__ __forceinline__ h2 rowsum16(h2 x){
  int v = ibc(x);
  v = ibc(hbc(v) + hbc(__builtin_amdgcn_mov_dpp(v, 0x121, 0xF, 0xF, true))); // row_ror:1
  v = ibc(hbc(v) + hbc(__builtin_amdgcn_mov_dpp(v, 0x122, 0xF, 0xF, true))); // row_ror:2
  v = ibc(hbc(v) + hbc(__builtin_amdgcn_mov_dpp(v, 0x124, 0xF, 0xF, true))); // row_ror:4
  v = ibc(hbc(v) + hbc(__builtin_amdgcn_mov_dpp(v, 0x128, 0xF, 0xF, true))); // row_ror:8
  return hbc(v);
}

__device__ __forceinline__ void updp(h2& s, h2& c, h2 cA, h2 sA, h2 GS, h2 GC){
  h2 e  = c*GS - s*GC;        // eps (radians), |e| <= 0.02
  h2 s1 = s*cA + c*sA;
  h2 c1 = c*cA - s*sA;
  s = s1 + c1*e;
  c = c1 - s1*e;
}

__device__ __forceinline__ h2 splat2(_Float16 v){ h2 r; r[0]=v; r[1]=v; return r; }

__global__ __launch_bounds__(256) void gemmiter_k(const u16* __restrict__ xb,
    const u16* __restrict__ wb, u16* __restrict__ phase0, float* __restrict__ amp,
    unsigned* __restrict__ cnt){
  __shared__ u16 lds[2][8192];          // [buf][16 KB]: A at 0, B at u16 4096
  const int tid = threadIdx.x;
  const int l   = tid & 63;
  const int w   = tid >> 6;

  const int bid = blockIdx.x;
  const int xcd = bid & 7;
  const int r   = bid >> 3;             // 0..87 within this XCD
  const int mt  = xcd * 8 + r / 11;
  const int nt  = r % 11;
  const int m0  = mt * 64;
  const int n0  = nt * 64;

  {
    const int srow = w*16 + (l >> 3);
    const int scol = (((l & 7) ^ (l >> 3)) * 8);      // inverse-swizzled k-slot
    const u16* ga = xb + (size_t)(m0 + srow) * N_DIMS + scol;
    const u16* gb = wb + (size_t)(n0 + srow) * N_DIMS + scol;

    #define STAGE(b, kt) { \
      const u16* gA = ga + (kt)*64; \
      const u16* gB = gb + (kt)*64; \
      gload16(gA,            &lds[b][w*1024]); \
      gload16(gA + 8*N_DIMS, &lds[b][w*1024 + 512]); \
      gload16(gB,            &lds[b][4096 + w*1024]); \
      gload16(gB + 8*N_DIMS, &lds[b][4096 + w*1024 + 512]); }

    const int rl = l & 15;
    const int q0 = l >> 4;
    const int sx = l & 7;
    const int wr = w >> 1, wc = w & 1;

    f32x4 acc[2][2] = {};
    STAGE(0, 0)
    __syncthreads();

    for (int kt = 0; kt < 16; kt++){
      const int cb = kt & 1;
      if (kt < 15) STAGE(cb^1, kt+1)
      s16x8 a[2][2], b[2][2];
      #pragma unroll
      for (int mi = 0; mi < 2; mi++)
      #pragma unroll
      for (int ks = 0; ks < 2; ks++){
        int off = (wr*32 + mi*16 + rl)*64 + (((ks*4 + q0) ^ sx) * 8);
        a[mi][ks] = *(const s16x8*)&lds[cb][off];
      }
      #pragma unroll
      for (int nj = 0; nj < 2; nj++)
      #pragma unroll
      for (int ks = 0; ks < 2; ks++){
        int off = 4096 + (wc*32 + nj*16 + rl)*64 + (((ks*4 + q0) ^ sx) * 8);
        b[nj][ks] = *(const s16x8*)&lds[cb][off];
      }
      #pragma unroll
      for (int ks = 0; ks < 2; ks++)
      #pragma unroll
      for (int mi = 0; mi < 2; mi++)
      #pragma unroll
      for (int nj = 0; nj < 2; nj++)
        acc[mi][nj] = __builtin_amdgcn_mfma_f32_16x16x32_bf16(a[mi][ks], b[nj][ks], acc[mi][nj], 0,0,0);
      __syncthreads();
    }
    #undef STAGE

    // C/D layout: col = lane&15, row = (lane>>4)*4 + reg
    #pragma unroll
    for (int mi = 0; mi < 2; mi++)
    #pragma unroll
    for (int nj = 0; nj < 2; nj++){
      const int n = n0 + wc*32 + nj*16 + rl;
      #pragma unroll
      for (int rg = 0; rg < 4; rg++){
        const int m = m0 + wr*32 + mi*16 + q0*4 + rg;
        float v = acc[mi][nj][rg];
        if (n < N_OSC) { float t = v * INV2PI; t -= floorf(t); phase0[(size_t)m*N_OSC + n] = f2bf(t); }
        else           { amp[(size_t)m*N_OSC + (n - N_OSC)] = fmaxf(fabsf(v), EPSV); }
      }
    }
  }

  // ---- strip handshake (same XCD / same L2) ----
  __threadfence();
  if (tid == 0)
    __hip_atomic_fetch_add(&cnt[mt], 1u, __ATOMIC_RELEASE, __HIP_MEMORY_SCOPE_AGENT);

  const int g = nt + 11*w;              // 4-row group within the strip
  if (g >= 16) return;                  // waves 2..3 (and some wave-1) exit

  {
    unsigned v = 0;
    for (;;){
      if (l == 0 && (tid >> 6) == (tid >> 6))  // lane 0 of this wave polls
        v = (l == 0) ? __hip_atomic_load(&cnt[mt], __ATOMIC_RELAXED, __HIP_MEMORY_SCOPE_AGENT) : v;
      v = __shfl(v, 0, 64);
      if (v >= 11u) break;
      __builtin_amdgcn_s_sleep(16);
    }
  }
  __threadfence();

  // ---- iteration (v2) for rows mt*64 + g*4 .. +3 ----
  const int g16 = l & 15;
  const int row = m0 + g*4 + (l >> 4);
  const size_t rb = (size_t)row * N_OSC;

  const h2 cAd = splat2((_Float16)0.99211470f), sAd = splat2((_Float16)0.12533323f);
  const h2 cAt = splat2((_Float16)0.92977649f), sAt = splat2((_Float16)0.36812455f);
  const h2 cAg = splat2((_Float16)-0.80901699f), sAg = splat2((_Float16)0.58778525f);
  const h2 kd = splat2((_Float16)6.25e-4f);    // DT*COUPLING/32
  const h2 kt = splat2((_Float16)3.125e-4f);   // /64
  const h2 kg = splat2((_Float16)7.8125e-5f);  // /256

  h2 sD, cD, sT[2], cT[2], sG[8], cG[8];
  {
    const u16* pr = phase0 + rb;
    unsigned dw = *(const unsigned*)(pr + 2*g16);
    uint2 tw    = *(const uint2*)(pr + 32 + 4*g16);
    uint4 g0w   = *(const uint4*)(pr + 96 + 16*g16);
    uint4 g1w   = *(const uint4*)(pr + 96 + 16*g16 + 8);
    #define SC2(dS, dC, i, p0, p1) { \
      dS[i][0] = (_Float16)__builtin_amdgcn_sinf(p0); \
      dS[i][1] = (_Float16)__builtin_amdgcn_sinf(p1); \
      dC[i][0] = (_Float16)__builtin_amdgcn_cosf(p0); \
      dC[i][1] = (_Float16)__builtin_amdgcn_cosf(p1); }
    {
      float d0 = bf2f(dw & 0xFFFFu), d1 = bf2f(dw >> 16);
      sD[0] = (_Float16)__builtin_amdgcn_sinf(d0);
      sD[1] = (_Float16)__builtin_amdgcn_sinf(d1);
      cD[0] = (_Float16)__builtin_amdgcn_cosf(d0);
      cD[1] = (_Float16)__builtin_amdgcn_cosf(d1);
    }
    SC2(sT, cT, 0, bf2f(tw.x & 0xFFFFu), bf2f(tw.x >> 16))
    SC2(sT, cT, 1, bf2f(tw.y & 0xFFFFu), bf2f(tw.y >> 16))
    SC2(sG, cG, 0, bf2f(g0w.x & 0xFFFFu), bf2f(g0w.x >> 16))
    SC2(sG, cG, 1, bf2f(g0w.y & 0xFFFFu), bf2f(g0w.y >> 16))
    SC2(sG, cG, 2, bf2f(g0w.z & 0xFFFFu), bf2f(g0w.z >> 16))
    SC2(sG, cG, 3, bf2f(g0w.w & 0xFFFFu), bf2f(g0w.w >> 16))
    SC2(sG, cG, 4, bf2f(g1w.x & 0xFFFFu), bf2f(g1w.x >> 16))
    SC2(sG, cG, 5, bf2f(g1w.y & 0xFFFFu), bf2f(g1w.y >> 16))
    SC2(sG, cG, 6, bf2f(g1w.z & 0xFFFFu), bf2f(g1w.z >> 16))
    SC2(sG, cG, 7, bf2f(g1w.w & 0xFFFFu), bf2f(g1w.w >> 16))
    #undef SC2
  }

  h2 PD, PT, PG;
  #define REDUCE { \
    h2 pd; pd[0] = sD[0]+sD[1]; pd[1] = cD[0]+cD[1]; \
    h2 ts = sT[0]+sT[1], tc = cT[0]+cT[1]; \
    h2 pt; pt[0] = ts[0]+ts[1]; pt[1] = tc[0]+tc[1]; \
    h2 gs = ((sG[0]+sG[1])+(sG[2]+sG[3]))+((sG[4]+sG[5])+(sG[6]+sG[7])); \
    h2 gc = ((cG[0]+cG[1])+(cG[2]+cG[3]))+((cG[4]+cG[5])+(cG[6]+cG[7])); \
    h2 pg; pg[0] = gs[0]+gs[1]; pg[1] = gc[0]+gc[1]; \
    PD = rowsum16(pd); PT = rowsum16(pt); PG = rowsum16(pg); }

  REDUCE

  float Pth = 1.f, Pga = 1.f, mPth = 1.f, mPga = 1.f;
  for (int t = 0; t < 32; t++){
    h2 gd = PD * kd, gt = PT * kt, gg = PG * kg;
    h2 GSd = splat2(gd[0]), GCd = splat2(gd[1]);
    h2 GSt = splat2(gt[0]), GCt = splat2(gt[1]);
    h2 GSg = splat2(gg[0]), GCg = splat2(gg[1]);
    updp(sD, cD, cAd, sAd, GSd, GCd);
    updp(sT[0], cT[0], cAt, sAt, GSt, GCt);
    updp(sT[1], cT[1], cAt, sAt, GSt, GCt);
    #pragma unroll
    for (int i = 0; i < 8; i++) updp(sG[i], cG[i], cAg, sAg, GSg, GCg);
    REDUCE
    float Sd = (float)PD[0], Cd = (float)PD[1];
    float St = (float)PT[0], Ct = (float)PT[1];
    float ft = 1.f + 0.003f * Cd * __builtin_amdgcn_rsqf(Cd*Cd + Sd*Sd);
    float fg = 1.f + 0.003f * Ct * __builtin_amdgcn_rsqf(Ct*Ct + St*St);
    Pth *= ft; mPth = fminf(mPth, Pth);
    Pga *= fg; mPga = fminf(mPga, Pga);
  }
  #undef REDUCE

  const float cth = EPSV * Pth / mPth;
  const float cga = EPSV * Pga / mPga;
  {
    float4 a = *(const float4*)(amp + rb + 32 + 4*g16);
    a.x = fmaxf(a.x*Pth, cth); a.y = fmaxf(a.y*Pth, cth);
    a.z = fmaxf(a.z*Pth, cth); a.w = fmaxf(a.w*Pth, cth);
    *(float4*)(amp + rb + 32 + 4*g16) = a;
  }
  #pragma unroll
  for (int i = 0; i < 4; i++){
    float4 a = *(const float4*)(amp + rb + 96 + 16*g16 + 4*i);
    a.x = fmaxf(a.x*Pga, cga); a.y = fmaxf(a.y*Pga, cga);
    a.z = fmaxf(a.z*Pga, cga); a.w = fmaxf(a.w*Pga, cga);
    *(float4*)(amp + rb + 96 + 16*g16 + 4*i) = a;
  }
}

// ---------------- launch ----------------
extern "C" void kernel_launch(void* const* d_in, const int* in_sizes, int n_in,
                              void* d_out, int out_size, void* d_ws, size_t ws_size,
                              hipStream_t stream){
  const float* x  = (const float*)d_in[0];
  const float* wp = (const float*)d_in[1];
  const float* wa = (const float*)d_in[2];
  float* out = (float*)d_out;
  char* ws = (char*)d_ws;
  u16* xb  = (u16*)(ws);                    // 8,388,608 B
  u16* wb  = (u16*)(ws + 8388608);          // 1,441,792 B
  u16* phase0 = (u16*)(ws + 9830400);       // 2,883,584 B (bf16)
  unsigned* cnt = (unsigned*)(ws + 12713984); // 256 B strip counters

  convert_k<<<4800, 256, 0, stream>>>((const f32x4*)x, (const f32x4*)wp, (const f32x4*)wa,
                                      (u16x4*)xb, (u16x4*)wb, cnt);
  gemmiter_k<<<704, 256, 0, stream>>>(xb, wb, phase0, out, cnt);
}

// Round 14
// 58.948 us; speedup vs baseline: 5.9065x; 2.6775x over previous
//
#include <hip/hip_runtime.h>

typedef float  f32x4 __attribute__((ext_vector_type(4)));
typedef short  s16x8 __attribute__((ext_vector_type(8)));
typedef _Float16 h2 __attribute__((ext_vector_type(2)));
typedef unsigned short u16;
typedef u16 u16x4 __attribute__((ext_vector_type(4)));

#define N_DIMS 1024
#define N_OSC  352
#define BATCH  4096
#define EPSV   1e-6f
#define INV2PI 0.15915494309189535f

__device__ __forceinline__ u16 f2bf(float f){
  unsigned u = __builtin_bit_cast(unsigned, f);
  u += 0x7FFFu + ((u >> 16) & 1u);   // round-to-nearest-even
  return (u16)(u >> 16);
}
__device__ __forceinline__ float bf2f(unsigned h){
  return __builtin_bit_cast(float, h << 16);
}

#define NX4 1048576   // 4096*1024/4
#define NW4 90112     // 352*1024/4 (per weight matrix)

// ---------------- convert f32 -> bf16 (R11) ----------------
__global__ __launch_bounds__(256) void convert_k(const f32x4* __restrict__ x,
    const f32x4* __restrict__ wp, const f32x4* __restrict__ wa,
    u16x4* __restrict__ xb, u16x4* __restrict__ wb){
  int i = blockIdx.x * 256 + threadIdx.x;
  f32x4 v; u16x4* dst;
  if (i < NX4) { v = x[i]; dst = xb + i; }
  else {
    int j = i - NX4;
    v = (j < NW4) ? wp[j] : wa[j - NW4];
    dst = wb + j;
  }
  u16x4 r;
  r[0]=f2bf(v[0]); r[1]=f2bf(v[1]); r[2]=f2bf(v[2]); r[3]=f2bf(v[3]);
  *dst = r;
}

// ---------------- GEMM (R11 structure; amp0 -> ws) ----------------
__device__ __forceinline__ void gload16(const u16* g, u16* l){
  __builtin_amdgcn_global_load_lds(
      (const __attribute__((address_space(1))) unsigned int*)(g),
      (__attribute__((address_space(3))) unsigned int*)(l), 16, 0, 0);
}

__global__ __launch_bounds__(256) void gemm_k(const u16* __restrict__ xb,
    const u16* __restrict__ wb, u16* __restrict__ phase0, float* __restrict__ amp0){
  __shared__ u16 lds[2][8192];          // [buf][16 KB]: A at 0, B at u16 4096
  const int tid = threadIdx.x;
  const int l   = tid & 63;
  const int w   = tid >> 6;

  const int bid = blockIdx.x;
  const int xcd = bid & 7;
  const int r   = bid >> 3;             // 0..87 within this XCD
  const int mt  = xcd * 8 + r / 11;
  const int nt  = r % 11;
  const int m0  = mt * 64;
  const int n0  = nt * 64;

  const int srow = w*16 + (l >> 3);
  const int scol = (((l & 7) ^ (l >> 3)) * 8);      // inverse-swizzled k-slot
  const u16* ga = xb + (size_t)(m0 + srow) * N_DIMS + scol;
  const u16* gb = wb + (size_t)(n0 + srow) * N_DIMS + scol;

  #define STAGE(b, kt) { \
    const u16* gA = ga + (kt)*64; \
    const u16* gB = gb + (kt)*64; \
    gload16(gA,            &lds[b][w*1024]); \
    gload16(gA + 8*N_DIMS, &lds[b][w*1024 + 512]); \
    gload16(gB,            &lds[b][4096 + w*1024]); \
    gload16(gB + 8*N_DIMS, &lds[b][4096 + w*1024 + 512]); }

  const int rl = l & 15;
  const int q0 = l >> 4;
  const int sx = l & 7;
  const int wr = w >> 1, wc = w & 1;

  f32x4 acc[2][2] = {};
  STAGE(0, 0)
  __syncthreads();

  for (int kt = 0; kt < 16; kt++){
    const int cb = kt & 1;
    if (kt < 15) STAGE(cb^1, kt+1)
    s16x8 a[2][2], b[2][2];
    #pragma unroll
    for (int mi = 0; mi < 2; mi++)
    #pragma unroll
    for (int ks = 0; ks < 2; ks++){
      int off = (wr*32 + mi*16 + rl)*64 + (((ks*4 + q0) ^ sx) * 8);
      a[mi][ks] = *(const s16x8*)&lds[cb][off];
    }
    #pragma unroll
    for (int nj = 0; nj < 2; nj++)
    #pragma unroll
    for (int ks = 0; ks < 2; ks++){
      int off = 4096 + (wc*32 + nj*16 + rl)*64 + (((ks*4 + q0) ^ sx) * 8);
      b[nj][ks] = *(const s16x8*)&lds[cb][off];
    }
    #pragma unroll
    for (int ks = 0; ks < 2; ks++)
    #pragma unroll
    for (int mi = 0; mi < 2; mi++)
    #pragma unroll
    for (int nj = 0; nj < 2; nj++)
      acc[mi][nj] = __builtin_amdgcn_mfma_f32_16x16x32_bf16(a[mi][ks], b[nj][ks], acc[mi][nj], 0,0,0);
    __syncthreads();
  }
  #undef STAGE

  // C/D layout: col = lane&15, row = (lane>>4)*4 + reg
  #pragma unroll
  for (int mi = 0; mi < 2; mi++)
  #pragma unroll
  for (int nj = 0; nj < 2; nj++){
    const int n = n0 + wc*32 + nj*16 + rl;
    #pragma unroll
    for (int rg = 0; rg < 4; rg++){
      const int m = m0 + wr*32 + mi*16 + q0*4 + rg;
      float v = acc[mi][nj][rg];
      if (n < N_OSC) { float t = v * INV2PI; t -= floorf(t); phase0[(size_t)m*N_OSC + n] = f2bf(t); }
      else           { amp0[(size_t)m*N_OSC + (n - N_OSC)] = fmaxf(fabsf(v), EPSV); }
    }
  }
}

// ---------------- iteration (v2; IDEMPOTENT: reads amp0(ws), writes out) ----------------
__device__ __forceinline__ int ibc(h2 v){ return __builtin_bit_cast(int, v); }
__device__ __forceinline__ h2  hbc(int v){ return __builtin_bit_cast(h2, v); }

__device__ __forceinline__ h2 rowsum16(h2 x){
  int v = ibc(x);
  v = ibc(hbc(v) + hbc(__builtin_amdgcn_mov_dpp(v, 0x121, 0xF, 0xF, true))); // row_ror:1
  v = ibc(hbc(v) + hbc(__builtin_amdgcn_mov_dpp(v, 0x122, 0xF, 0xF, true))); // row_ror:2
  v = ibc(hbc(v) + hbc(__builtin_amdgcn_mov_dpp(v, 0x124, 0xF, 0xF, true))); // row_ror:4
  v = ibc(hbc(v) + hbc(__builtin_amdgcn_mov_dpp(v, 0x128, 0xF, 0xF, true))); // row_ror:8
  return hbc(v);
}

__device__ __forceinline__ void updp(h2& s, h2& c, h2 cA, h2 sA, h2 GS, h2 GC){
  h2 e  = c*GS - s*GC;        // eps (radians), |e| <= 0.02
  h2 s1 = s*cA + c*sA;
  h2 c1 = c*cA - s*sA;
  s = s1 + c1*e;
  c = c1 - s1*e;
}

__device__ __forceinline__ h2 splat2(_Float16 v){ h2 r; r[0]=v; r[1]=v; return r; }

__global__ __launch_bounds__(256) void iter_k(const u16* __restrict__ phase0,
                                              const float* __restrict__ amp0,
                                              float* __restrict__ out){
  const int tid = threadIdx.x;
  const int l   = tid & 63;
  const int g   = l & 15;
  const int row = blockIdx.x*16 + (tid>>6)*4 + (l>>4);
  const size_t rb = (size_t)row * N_OSC;

  const h2 cAd = splat2((_Float16)0.99211470f), sAd = splat2((_Float16)0.12533323f);
  const h2 cAt = splat2((_Float16)0.92977649f), sAt = splat2((_Float16)0.36812455f);
  const h2 cAg = splat2((_Float16)-0.80901699f), sAg = splat2((_Float16)0.58778525f);
  const h2 kd = splat2((_Float16)6.25e-4f);    // DT*COUPLING/32
  const h2 kt = splat2((_Float16)3.125e-4f);   // /64
  const h2 kg = splat2((_Float16)7.8125e-5f);  // /256

  h2 sD, cD, sT[2], cT[2], sG[8], cG[8];
  {
    const u16* pr = phase0 + rb;
    unsigned dw = *(const unsigned*)(pr + 2*g);
    uint2 tw    = *(const uint2*)(pr + 32 + 4*g);
    uint4 g0w   = *(const uint4*)(pr + 96 + 16*g);
    uint4 g1w   = *(const uint4*)(pr + 96 + 16*g + 8);
    #define SC2(dS, dC, i, p0, p1) { \
      dS[i][0] = (_Float16)__builtin_amdgcn_sinf(p0); \
      dS[i][1] = (_Float16)__builtin_amdgcn_sinf(p1); \
      dC[i][0] = (_Float16)__builtin_amdgcn_cosf(p0); \
      dC[i][1] = (_Float16)__builtin_amdgcn_cosf(p1); }
    {
      float d0 = bf2f(dw & 0xFFFFu), d1 = bf2f(dw >> 16);
      sD[0] = (_Float16)__builtin_amdgcn_sinf(d0);
      sD[1] = (_Float16)__builtin_amdgcn_sinf(d1);
      cD[0] = (_Float16)__builtin_amdgcn_cosf(d0);
      cD[1] = (_Float16)__builtin_amdgcn_cosf(d1);
    }
    SC2(sT, cT, 0, bf2f(tw.x & 0xFFFFu), bf2f(tw.x >> 16))
    SC2(sT, cT, 1, bf2f(tw.y & 0xFFFFu), bf2f(tw.y >> 16))
    SC2(sG, cG, 0, bf2f(g0w.x & 0xFFFFu), bf2f(g0w.x >> 16))
    SC2(sG, cG, 1, bf2f(g0w.y & 0xFFFFu), bf2f(g0w.y >> 16))
    SC2(sG, cG, 2, bf2f(g0w.z & 0xFFFFu), bf2f(g0w.z >> 16))
    SC2(sG, cG, 3, bf2f(g0w.w & 0xFFFFu), bf2f(g0w.w >> 16))
    SC2(sG, cG, 4, bf2f(g1w.x & 0xFFFFu), bf2f(g1w.x >> 16))
    SC2(sG, cG, 5, bf2f(g1w.y & 0xFFFFu), bf2f(g1w.y >> 16))
    SC2(sG, cG, 6, bf2f(g1w.z & 0xFFFFu), bf2f(g1w.z >> 16))
    SC2(sG, cG, 7, bf2f(g1w.w & 0xFFFFu), bf2f(g1w.w >> 16))
    #undef SC2
  }

  h2 PD, PT, PG;
  #define REDUCE { \
    h2 pd; pd[0] = sD[0]+sD[1]; pd[1] = cD[0]+cD[1]; \
    h2 ts = sT[0]+sT[1], tc = cT[0]+cT[1]; \
    h2 pt; pt[0] = ts[0]+ts[1]; pt[1] = tc[0]+tc[1]; \
    h2 gs = ((sG[0]+sG[1])+(sG[2]+sG[3]))+((sG[4]+sG[5])+(sG[6]+sG[7])); \
    h2 gc = ((cG[0]+cG[1])+(cG[2]+cG[3]))+((cG[4]+cG[5])+(cG[6]+cG[7])); \
    h2 pg; pg[0] = gs[0]+gs[1]; pg[1] = gc[0]+gc[1]; \
    PD = rowsum16(pd); PT = rowsum16(pt); PG = rowsum16(pg); }

  REDUCE

  float Pth = 1.f, Pga = 1.f, mPth = 1.f, mPga = 1.f;
  for (int t = 0; t < 32; t++){
    h2 gd = PD * kd, gt = PT * kt, gg = PG * kg;
    h2 GSd = splat2(gd[0]), GCd = splat2(gd[1]);
    h2 GSt = splat2(gt[0]), GCt = splat2(gt[1]);
    h2 GSg = splat2(gg[0]), GCg = splat2(gg[1]);
    updp(sD, cD, cAd, sAd, GSd, GCd);
    updp(sT[0], cT[0], cAt, sAt, GSt, GCt);
    updp(sT[1], cT[1], cAt, sAt, GSt, GCt);
    #pragma unroll
    for (int i = 0; i < 8; i++) updp(sG[i], cG[i], cAg, sAg, GSg, GCg);
    REDUCE
    float Sd = (float)PD[0], Cd = (float)PD[1];
    float St = (float)PT[0], Ct = (float)PT[1];
    float ft = 1.f + 0.003f * Cd * __builtin_amdgcn_rsqf(Cd*Cd + Sd*Sd);
    float fg = 1.f + 0.003f * Ct * __builtin_amdgcn_rsqf(Ct*Ct + St*St);
    Pth *= ft; mPth = fminf(mPth, Pth);
    Pga *= fg; mPga = fminf(mPga, Pga);
  }
  #undef REDUCE

  const float cth = EPSV * Pth / mPth;
  const float cga = EPSV * Pga / mPga;
  {
    // delta pass-through (factor 1; eps already applied by gemm)
    float2 d = *(const float2*)(amp0 + rb + 2*g);
    *(float2*)(out + rb + 2*g) = d;
  }
  {
    float4 a = *(const float4*)(amp0 + rb + 32 + 4*g);
    a.x = fmaxf(a.x*Pth, cth); a.y = fmaxf(a.y*Pth, cth);
    a.z = fmaxf(a.z*Pth, cth); a.w = fmaxf(a.w*Pth, cth);
    *(float4*)(out + rb + 32 + 4*g) = a;
  }
  #pragma unroll
  for (int i = 0; i < 4; i++){
    float4 a = *(const float4*)(amp0 + rb + 96 + 16*g + 4*i);
    a.x = fmaxf(a.x*Pga, cga); a.y = fmaxf(a.y*Pga, cga);
    a.z = fmaxf(a.z*Pga, cga); a.w = fmaxf(a.w*Pga, cga);
    *(float4*)(out + rb + 96 + 16*g + 4*i) = a;
  }
}

// ---------------- launch ----------------
// ATTRIBUTION PROBE: iter_k launched 4x (idempotent: amp0 in ws -> out).
// iter+node ~= (dur_R14 - dur_R11)/3.
extern "C" void kernel_launch(void* const* d_in, const int* in_sizes, int n_in,
                              void* d_out, int out_size, void* d_ws, size_t ws_size,
                              hipStream_t stream){
  const float* x  = (const float*)d_in[0];
  const float* wp = (const float*)d_in[1];
  const float* wa = (const float*)d_in[2];
  float* out = (float*)d_out;
  char* ws = (char*)d_ws;
  u16* xb  = (u16*)(ws);                    // 8,388,608 B
  u16* wb  = (u16*)(ws + 8388608);          // 1,441,792 B
  u16* phase0 = (u16*)(ws + 9830400);       // 2,883,584 B (bf16)
  float* amp0 = (float*)(ws + 12713984);    // 5,767,168 B

  convert_k<<<4800, 256, 0, stream>>>((const f32x4*)x, (const f32x4*)wp, (const f32x4*)wa,
                                      (u16x4*)xb, (u16x4*)wb);
  gemm_k<<<704, 256, 0, stream>>>(xb, wb, phase0, amp0);
  iter_k<<<256, 256, 0, stream>>>(phase0, amp0, out);
  iter_k<<<256, 256, 0, stream>>>(phase0, amp0, out);
  iter_k<<<256, 256, 0, stream>>>(phase0, amp0, out);
  iter_k<<<256, 256, 0, stream>>>(phase0, amp0, out);
}

// Round 15
// 31.538 us; speedup vs baseline: 11.0398x; 1.8691x over previous
//
#include <hip/hip_runtime.h>

typedef float  f32x4 __attribute__((ext_vector_type(4)));
typedef short  s16x8 __attribute__((ext_vector_type(8)));
typedef _Float16 h2 __attribute__((ext_vector_type(2)));
typedef unsigned short u16;
typedef u16 u16x4 __attribute__((ext_vector_type(4)));

#define N_DIMS 1024
#define N_OSC  352
#define N_PH   96            // only delta(32)+theta(64) phases are live
#define NTOT   448           // 96 phase cols + 352 amp cols
#define BATCH  4096
#define EPSV   1e-6f
#define INV2PI 0.15915494309189535f

__device__ __forceinline__ u16 f2bf(float f){
  unsigned u = __builtin_bit_cast(unsigned, f);
  u += 0x7FFFu + ((u >> 16) & 1u);   // round-to-nearest-even
  return (u16)(u >> 16);
}
__device__ __forceinline__ float bf2f(unsigned h){
  return __builtin_bit_cast(float, h << 16);
}

#define NX4 1048576   // 4096*1024/4
#define NWP4 24576    // 96*1024/4  (live W_phase rows)
#define NWA4 90112    // 352*1024/4
#define NCONV (NX4 + NWP4 + NWA4)   // 1,163,264

// wb[448][1024] = W_phase rows 0..95, then W_amp rows 0..351
__global__ __launch_bounds__(256) void convert_k(const f32x4* __restrict__ x,
    const f32x4* __restrict__ wp, const f32x4* __restrict__ wa,
    u16x4* __restrict__ xb, u16x4* __restrict__ wb){
  int i = blockIdx.x * 256 + threadIdx.x;
  if (i >= NCONV) return;
  f32x4 v; u16x4* dst;
  if (i < NX4) { v = x[i]; dst = xb + i; }
  else {
    int j = i - NX4;
    v = (j < NWP4) ? wp[j] : wa[j - NWP4];
    dst = wb + j;
  }
  u16x4 r;
  r[0]=f2bf(v[0]); r[1]=f2bf(v[1]); r[2]=f2bf(v[2]); r[3]=f2bf(v[3]);
  *dst = r;
}

// ---------------- GEMM: [phase0[4096][96] | amp0[4096][352]] = x @ wb^T ----------------
// R11 structure: BM=BN=BK=64, 4 waves (2x2), 16x16x32 MFMA acc[2][2], dbuf LDS,
// global_load_lds w=16, T2 swizzle via inverse-swizzled source.
// XCD-bijective: 448 blocks = 8 XCDs x (8 m-tiles x 7 n-tiles).
__device__ __forceinline__ void gload16(const u16* g, u16* l){
  __builtin_amdgcn_global_load_lds(
      (const __attribute__((address_space(1))) unsigned int*)(g),
      (__attribute__((address_space(3))) unsigned int*)(l), 16, 0, 0);
}

__global__ __launch_bounds__(256) void gemm_k(const u16* __restrict__ xb,
    const u16* __restrict__ wb, u16* __restrict__ phase0, float* __restrict__ amp0){
  __shared__ u16 lds[2][8192];          // [buf][16 KB]: A at 0, B at u16 4096
  const int tid = threadIdx.x;
  const int l   = tid & 63;
  const int w   = tid >> 6;

  const int bid = blockIdx.x;
  const int xcd = bid & 7;
  const int r   = bid >> 3;             // 0..55 within this XCD
  const int mt  = xcd * 8 + r / 7;      // 8 contiguous m-tiles per XCD
  const int nt  = r % 7;
  const int m0  = mt * 64;
  const int n0  = nt * 64;

  const int srow = w*16 + (l >> 3);
  const int scol = (((l & 7) ^ (l >> 3)) * 8);      // inverse-swizzled k-slot
  const u16* ga = xb + (size_t)(m0 + srow) * N_DIMS + scol;
  const u16* gb = wb + (size_t)(n0 + srow) * N_DIMS + scol;

  #define STAGE(b, kt) { \
    const u16* gA = ga + (kt)*64; \
    const u16* gB = gb + (kt)*64; \
    gload16(gA,            &lds[b][w*1024]); \
    gload16(gA + 8*N_DIMS, &lds[b][w*1024 + 512]); \
    gload16(gB,            &lds[b][4096 + w*1024]); \
    gload16(gB + 8*N_DIMS, &lds[b][4096 + w*1024 + 512]); }

  const int rl = l & 15;
  const int q0 = l >> 4;
  const int sx = l & 7;
  const int wr = w >> 1, wc = w & 1;

  f32x4 acc[2][2] = {};
  STAGE(0, 0)
  __syncthreads();

  for (int kt = 0; kt < 16; kt++){
    const int cb = kt & 1;
    if (kt < 15) STAGE(cb^1, kt+1)
    s16x8 a[2][2], b[2][2];
    #pragma unroll
    for (int mi = 0; mi < 2; mi++)
    #pragma unroll
    for (int ks = 0; ks < 2; ks++){
      int off = (wr*32 + mi*16 + rl)*64 + (((ks*4 + q0) ^ sx) * 8);
      a[mi][ks] = *(const s16x8*)&lds[cb][off];
    }
    #pragma unroll
    for (int nj = 0; nj < 2; nj++)
    #pragma unroll
    for (int ks = 0; ks < 2; ks++){
      int off = 4096 + (wc*32 + nj*16 + rl)*64 + (((ks*4 + q0) ^ sx) * 8);
      b[nj][ks] = *(const s16x8*)&lds[cb][off];
    }
    #pragma unroll
    for (int ks = 0; ks < 2; ks++)
    #pragma unroll
    for (int mi = 0; mi < 2; mi++)
    #pragma unroll
    for (int nj = 0; nj < 2; nj++)
      acc[mi][nj] = __builtin_amdgcn_mfma_f32_16x16x32_bf16(a[mi][ks], b[nj][ks], acc[mi][nj], 0,0,0);
    __syncthreads();
  }
  #undef STAGE

  // C/D layout: col = lane&15, row = (lane>>4)*4 + reg.  n-groups of 16 are
  // uniformly phase (n<96) or amp (n>=96) since 96 % 16 == 0.
  #pragma unroll
  for (int mi = 0; mi < 2; mi++)
  #pragma unroll
  for (int nj = 0; nj < 2; nj++){
    const int n = n0 + wc*32 + nj*16 + rl;
    #pragma unroll
    for (int rg = 0; rg < 4; rg++){
      const int m = m0 + wr*32 + mi*16 + q0*4 + rg;
      float v = acc[mi][nj][rg];
      if (n < N_PH) { float t = v * INV2PI; t -= floorf(t); phase0[(size_t)m*N_PH + n] = f2bf(t); }
      else          { amp0[(size_t)m*N_OSC + (n - N_PH)] = fmaxf(fabsf(v), EPSV); }
    }
  }
}

// ---------------- iteration: delta+theta only (gamma phases are dead code) ----------------
// 16 lanes/row, 4 rows/wave. Lane g owns delta {2g,2g+1} (1 h2) and theta
// {32+4g..+3} (2 h2). Per step: 3 h2 rotation updates + 2 DPP reductions.
// ft (from delta mean) scales theta amps; fg (from theta mean) scales gamma amps.
__device__ __forceinline__ int ibc(h2 v){ return __builtin_bit_cast(int, v); }
__device__ __forceinline__ h2  hbc(int v){ return __builtin_bit_cast(h2, v); }

__device__ __forceinline__ h2 rowsum16(h2 x){
  int v = ibc(x);
  v = ibc(hbc(v) + hbc(__builtin_amdgcn_mov_dpp(v, 0x121, 0xF, 0xF, true))); // row_ror:1
  v = ibc(hbc(v) + hbc(__builtin_amdgcn_mov_dpp(v, 0x122, 0xF, 0xF, true))); // row_ror:2
  v = ibc(hbc(v) + hbc(__builtin_amdgcn_mov_dpp(v, 0x124, 0xF, 0xF, true))); // row_ror:4
  v = ibc(hbc(v) + hbc(__builtin_amdgcn_mov_dpp(v, 0x128, 0xF, 0xF, true))); // row_ror:8
  return hbc(v);
}

__device__ __forceinline__ void updp(h2& s, h2& c, h2 cA, h2 sA, h2 GS, h2 GC){
  h2 e  = c*GS - s*GC;        // eps (radians), |e| <= 0.02
  h2 s1 = s*cA + c*sA;
  h2 c1 = c*cA - s*sA;
  s = s1 + c1*e;
  c = c1 - s1*e;
}

__device__ __forceinline__ h2 splat2(_Float16 v){ h2 r; r[0]=v; r[1]=v; return r; }

__global__ __launch_bounds__(256) void iter_k(const u16* __restrict__ phase0,
                                              float* __restrict__ amp){
  const int tid = threadIdx.x;
  const int l   = tid & 63;
  const int g   = l & 15;
  const int row = blockIdx.x*16 + (tid>>6)*4 + (l>>4);
  const size_t rb  = (size_t)row * N_OSC;   // amp row base
  const size_t rbp = (size_t)row * N_PH;    // phase row base

  const h2 cAd = splat2((_Float16)0.99211470f), sAd = splat2((_Float16)0.12533323f);
  const h2 cAt = splat2((_Float16)0.92977649f), sAt = splat2((_Float16)0.36812455f);
  const h2 kd = splat2((_Float16)6.25e-4f);    // DT*COUPLING/32
  const h2 kt = splat2((_Float16)3.125e-4f);   // /64

  h2 sD, cD, sT[2], cT[2];
  {
    const u16* pr = phase0 + rbp;
    unsigned dw = *(const unsigned*)(pr + 2*g);     // 2 bf16 (delta)
    uint2 tw    = *(const uint2*)(pr + 32 + 4*g);   // 4 bf16 (theta)
    #define SC2(dS, dC, i, p0, p1) { \
      dS[i][0] = (_Float16)__builtin_amdgcn_sinf(p0); \
      dS[i][1] = (_Float16)__builtin_amdgcn_sinf(p1); \
      dC[i][0] = (_Float16)__builtin_amdgcn_cosf(p0); \
      dC[i][1] = (_Float16)__builtin_amdgcn_cosf(p1); }
    {
      float d0 = bf2f(dw & 0xFFFFu), d1 = bf2f(dw >> 16);
      sD[0] = (_Float16)__builtin_amdgcn_sinf(d0);
      sD[1] = (_Float16)__builtin_amdgcn_sinf(d1);
      cD[0] = (_Float16)__builtin_amdgcn_cosf(d0);
      cD[1] = (_Float16)__builtin_amdgcn_cosf(d1);
    }
    SC2(sT, cT, 0, bf2f(tw.x & 0xFFFFu), bf2f(tw.x >> 16))
    SC2(sT, cT, 1, bf2f(tw.y & 0xFFFFu), bf2f(tw.y >> 16))
    #undef SC2
  }

  h2 PD, PT;
  #define REDUCE { \
    h2 pd; pd[0] = sD[0]+sD[1]; pd[1] = cD[0]+cD[1]; \
    h2 ts = sT[0]+sT[1], tc = cT[0]+cT[1]; \
    h2 pt; pt[0] = ts[0]+ts[1]; pt[1] = tc[0]+tc[1]; \
    PD = rowsum16(pd); PT = rowsum16(pt); }

  REDUCE

  float Pth = 1.f, Pga = 1.f, mPth = 1.f, mPga = 1.f;
  for (int t = 0; t < 32; t++){
    h2 gd = PD * kd, gt = PT * kt;      // (k*S, k*C)
    h2 GSd = splat2(gd[0]), GCd = splat2(gd[1]);
    h2 GSt = splat2(gt[0]), GCt = splat2(gt[1]);
    updp(sD, cD, cAd, sAd, GSd, GCd);
    updp(sT[0], cT[0], cAt, sAt, GSt, GCt);
    updp(sT[1], cT[1], cAt, sAt, GSt, GCt);
    REDUCE
    float Sd = (float)PD[0], Cd = (float)PD[1];
    float St = (float)PT[0], Ct = (float)PT[1];
    float ft = 1.f + 0.003f * Cd * __builtin_amdgcn_rsqf(Cd*Cd + Sd*Sd);
    float fg = 1.f + 0.003f * Ct * __builtin_amdgcn_rsqf(Ct*Ct + St*St);
    Pth *= ft; mPth = fminf(mPth, Pth);
    Pga *= fg; mPga = fminf(mPga, Pga);
  }
  #undef REDUCE

  const float cth = EPSV * Pth / mPth;
  const float cga = EPSV * Pga / mPga;
  {
    float4 a = *(const float4*)(amp + rb + 32 + 4*g);
    a.x = fmaxf(a.x*Pth, cth); a.y = fmaxf(a.y*Pth, cth);
    a.z = fmaxf(a.z*Pth, cth); a.w = fmaxf(a.w*Pth, cth);
    *(float4*)(amp + rb + 32 + 4*g) = a;
  }
  #pragma unroll
  for (int i = 0; i < 4; i++){
    float4 a = *(const float4*)(amp + rb + 96 + 16*g + 4*i);
    a.x = fmaxf(a.x*Pga, cga); a.y = fmaxf(a.y*Pga, cga);
    a.z = fmaxf(a.z*Pga, cga); a.w = fmaxf(a.w*Pga, cga);
    *(float4*)(amp + rb + 96 + 16*g + 4*i) = a;
  }
  // delta amps (factor 1): already final, written by gemm_k
}

// ---------------- launch ----------------
extern "C" void kernel_launch(void* const* d_in, const int* in_sizes, int n_in,
                              void* d_out, int out_size, void* d_ws, size_t ws_size,
                              hipStream_t stream){
  const float* x  = (const float*)d_in[0];
  const float* wp = (const float*)d_in[1];
  const float* wa = (const float*)d_in[2];
  float* out = (float*)d_out;
  char* ws = (char*)d_ws;
  u16* xb  = (u16*)(ws);                    // 8,388,608 B
  u16* wb  = (u16*)(ws + 8388608);          //   917,504 B (448 rows)
  u16* phase0 = (u16*)(ws + 9306112);       //   786,432 B (bf16, [4096][96])

  convert_k<<<4544, 256, 0, stream>>>((const f32x4*)x, (const f32x4*)wp, (const f32x4*)wa,
                                      (u16x4*)xb, (u16x4*)wb);
  gemm_k<<<448, 256, 0, stream>>>(xb, wb, phase0, out);
  iter_k<<<256, 256, 0, stream>>>(phase0, out);
}

// Round 16
// 31.107 us; speedup vs baseline: 11.1927x; 1.0138x over previous
//
#include <hip/hip_runtime.h>

typedef float  f32x4 __attribute__((ext_vector_type(4)));
typedef short  s16x8 __attribute__((ext_vector_type(8)));
typedef _Float16 h2 __attribute__((ext_vector_type(2)));
typedef unsigned short u16;
typedef u16 u16x4 __attribute__((ext_vector_type(4)));

#define N_DIMS 1024
#define N_OSC  352
#define N_PH   96            // only delta(32)+theta(64) phases are live
#define BATCH  4096
#define EPSV   1e-6f
#define INV2PI 0.15915494309189535f

__device__ __forceinline__ u16 f2bf(float f){
  unsigned u = __builtin_bit_cast(unsigned, f);
  u += 0x7FFFu + ((u >> 16) & 1u);   // round-to-nearest-even
  return (u16)(u >> 16);
}
__device__ __forceinline__ float bf2f(unsigned h){
  return __builtin_bit_cast(float, h << 16);
}

#define NX4 1048576   // 4096*1024/4
#define NWP4 24576    // 96*1024/4  (live W_phase rows)
#define NWA4 90112    // 352*1024/4
#define NCONV (NX4 + NWP4 + NWA4)   // 1,163,264

// wb[448][1024] = W_phase rows 0..95, then W_amp rows 0..351
__global__ __launch_bounds__(256) void convert_k(const f32x4* __restrict__ x,
    const f32x4* __restrict__ wp, const f32x4* __restrict__ wa,
    u16x4* __restrict__ xb, u16x4* __restrict__ wb){
  int i = blockIdx.x * 256 + threadIdx.x;
  if (i >= NCONV) return;
  f32x4 v; u16x4* dst;
  if (i < NX4) { v = x[i]; dst = xb + i; }
  else {
    int j = i - NX4;
    v = (j < NWP4) ? wp[j] : wa[j - NWP4];
    dst = wb + j;
  }
  u16x4 r;
  r[0]=f2bf(v[0]); r[1]=f2bf(v[1]); r[2]=f2bf(v[2]); r[3]=f2bf(v[3]);
  *dst = r;
}

// ---------------- GEMM: [phase0[4096][96] | amp0[4096][352]] = x @ wb^T ----------------
// BM=64, BN=32, BK=64 -> 64 x 14 = 896 blocks (3.5/CU; 24 KB LDS -> 6/CU capacity).
// Deeper grid fills per-block barrier/load-latency stalls (R15 was 1.75/CU).
// 4 waves (2m x 2n), wave tile 32x16 via 16x16x32 MFMA acc[2].
// global_load_lds w=16 staging, T2 swizzle via inverse-swizzled source.
// XCD-bijective: 896 = 8 XCDs x (8 m-tiles x 14 n-tiles).
__device__ __forceinline__ void gload16(const u16* g, u16* l){
  __builtin_amdgcn_global_load_lds(
      (const __attribute__((address_space(1))) unsigned int*)(g),
      (__attribute__((address_space(3))) unsigned int*)(l), 16, 0, 0);
}

__global__ __launch_bounds__(256) void gemm_k(const u16* __restrict__ xb,
    const u16* __restrict__ wb, u16* __restrict__ phase0, float* __restrict__ amp0){
  __shared__ u16 lds[2][6144];          // [buf][12 KB]: A 64x64 at 0, B 32x64 at u16 4096
  const int tid = threadIdx.x;
  const int l   = tid & 63;
  const int w   = tid >> 6;

  const int bid = blockIdx.x;
  const int xcd = bid & 7;
  const int r   = bid >> 3;             // 0..111 within this XCD
  const int mt  = xcd * 8 + r / 14;     // 8 contiguous m-tiles per XCD
  const int nt  = r % 14;
  const int m0  = mt * 64;
  const int n0  = nt * 32;

  // staging: A rows w*16..+15 (2 issues of 8 rows), B rows w*8..+7 (1 issue)
  const int sr8  = l >> 3;
  const int scol = (((l & 7) ^ sr8) * 8);           // inverse-swizzled k-slot
  const u16* ga = xb + (size_t)(m0 + w*16 + sr8) * N_DIMS + scol;
  const u16* gb = wb + (size_t)(n0 + w*8  + sr8) * N_DIMS + scol;

  #define STAGE(b, kt) { \
    gload16(ga + (kt)*64,            &lds[b][w*1024]); \
    gload16(ga + (kt)*64 + 8*N_DIMS, &lds[b][w*1024 + 512]); \
    gload16(gb + (kt)*64,            &lds[b][4096 + w*512]); }

  const int rl = l & 15;
  const int q0 = l >> 4;
  const int sx = l & 7;                 // row&7 for frag rows (A and B alike)
  const int wr = w >> 1, wc = w & 1;

  f32x4 acc[2] = {};
  STAGE(0, 0)
  __syncthreads();

  for (int kt = 0; kt < 16; kt++){
    const int cb = kt & 1;
    if (kt < 15) STAGE(cb^1, kt+1)
    s16x8 a[2][2], b[2];
    #pragma unroll
    for (int mi = 0; mi < 2; mi++)
    #pragma unroll
    for (int ks = 0; ks < 2; ks++){
      int off = (wr*32 + mi*16 + rl)*64 + (((ks*4 + q0) ^ sx) * 8);
      a[mi][ks] = *(const s16x8*)&lds[cb][off];
    }
    #pragma unroll
    for (int ks = 0; ks < 2; ks++){
      int off = 4096 + (wc*16 + rl)*64 + (((ks*4 + q0) ^ sx) * 8);
      b[ks] = *(const s16x8*)&lds[cb][off];
    }
    #pragma unroll
    for (int ks = 0; ks < 2; ks++)
    #pragma unroll
    for (int mi = 0; mi < 2; mi++)
      acc[mi] = __builtin_amdgcn_mfma_f32_16x16x32_bf16(a[mi][ks], b[ks], acc[mi], 0,0,0);
    __syncthreads();
  }
  #undef STAGE

  // C/D layout: col = lane&15, row = (lane>>4)*4 + reg.
  // n-block of 32 is uniformly phase (n0<96) or amp (96 = 3*32).
  const int n = n0 + wc*16 + rl;
  const bool isph = (n < N_PH);
  #pragma unroll
  for (int mi = 0; mi < 2; mi++)
  #pragma unroll
  for (int rg = 0; rg < 4; rg++){
    const int m = m0 + wr*32 + mi*16 + q0*4 + rg;
    float v = acc[mi][rg];
    if (isph){ float t = v * INV2PI; t -= floorf(t); phase0[(size_t)m*N_PH + n] = f2bf(t); }
    else     { amp0[(size_t)m*N_OSC + (n - N_PH)] = fmaxf(fabsf(v), EPSV); }
  }
}

// ---------------- iteration: delta+theta only (R15) ----------------
__device__ __forceinline__ int ibc(h2 v){ return __builtin_bit_cast(int, v); }
__device__ __forceinline__ h2  hbc(int v){ return __builtin_bit_cast(h2, v); }

__device__ __forceinline__ h2 rowsum16(h2 x){
  int v = ibc(x);
  v = ibc(hbc(v) + hbc(__builtin_amdgcn_mov_dpp(v, 0x121, 0xF, 0xF, true))); // row_ror:1
  v = ibc(hbc(v) + hbc(__builtin_amdgcn_mov_dpp(v, 0x122, 0xF, 0xF, true))); // row_ror:2
  v = ibc(hbc(v) + hbc(__builtin_amdgcn_mov_dpp(v, 0x124, 0xF, 0xF, true))); // row_ror:4
  v = ibc(hbc(v) + hbc(__builtin_amdgcn_mov_dpp(v, 0x128, 0xF, 0xF, true))); // row_ror:8
  return hbc(v);
}

__device__ __forceinline__ void updp(h2& s, h2& c, h2 cA, h2 sA, h2 GS, h2 GC){
  h2 e  = c*GS - s*GC;        // eps (radians), |e| <= 0.02
  h2 s1 = s*cA + c*sA;
  h2 c1 = c*cA - s*sA;
  s = s1 + c1*e;
  c = c1 - s1*e;
}

__device__ __forceinline__ h2 splat2(_Float16 v){ h2 r; r[0]=v; r[1]=v; return r; }

__global__ __launch_bounds__(256) void iter_k(const u16* __restrict__ phase0,
                                              float* __restrict__ amp){
  const int tid = threadIdx.x;
  const int l   = tid & 63;
  const int g   = l & 15;
  const int row = blockIdx.x*16 + (tid>>6)*4 + (l>>4);
  const size_t rb  = (size_t)row * N_OSC;   // amp row base
  const size_t rbp = (size_t)row * N_PH;    // phase row base

  const h2 cAd = splat2((_Float16)0.99211470f), sAd = splat2((_Float16)0.12533323f);
  const h2 cAt = splat2((_Float16)0.92977649f), sAt = splat2((_Float16)0.36812455f);
  const h2 kd = splat2((_Float16)6.25e-4f);    // DT*COUPLING/32
  const h2 kt = splat2((_Float16)3.125e-4f);   // /64

  h2 sD, cD, sT[2], cT[2];
  {
    const u16* pr = phase0 + rbp;
    unsigned dw = *(const unsigned*)(pr + 2*g);     // 2 bf16 (delta)
    uint2 tw    = *(const uint2*)(pr + 32 + 4*g);   // 4 bf16 (theta)
    #define SC2(dS, dC, i, p0, p1) { \
      dS[i][0] = (_Float16)__builtin_amdgcn_sinf(p0); \
      dS[i][1] = (_Float16)__builtin_amdgcn_sinf(p1); \
      dC[i][0] = (_Float16)__builtin_amdgcn_cosf(p0); \
      dC[i][1] = (_Float16)__builtin_amdgcn_cosf(p1); }
    {
      float d0 = bf2f(dw & 0xFFFFu), d1 = bf2f(dw >> 16);
      sD[0] = (_Float16)__builtin_amdgcn_sinf(d0);
      sD[1] = (_Float16)__builtin_amdgcn_sinf(d1);
      cD[0] = (_Float16)__builtin_amdgcn_cosf(d0);
      cD[1] = (_Float16)__builtin_amdgcn_cosf(d1);
    }
    SC2(sT, cT, 0, bf2f(tw.x & 0xFFFFu), bf2f(tw.x >> 16))
    SC2(sT, cT, 1, bf2f(tw.y & 0xFFFFu), bf2f(tw.y >> 16))
    #undef SC2
  }

  h2 PD, PT;
  #define REDUCE { \
    h2 pd; pd[0] = sD[0]+sD[1]; pd[1] = cD[0]+cD[1]; \
    h2 ts = sT[0]+sT[1], tc = cT[0]+cT[1]; \
    h2 pt; pt[0] = ts[0]+ts[1]; pt[1] = tc[0]+tc[1]; \
    PD = rowsum16(pd); PT = rowsum16(pt); }

  REDUCE

  float Pth = 1.f, Pga = 1.f, mPth = 1.f, mPga = 1.f;
  for (int t = 0; t < 32; t++){
    h2 gd = PD * kd, gt = PT * kt;      // (k*S, k*C)
    h2 GSd = splat2(gd[0]), GCd = splat2(gd[1]);
    h2 GSt = splat2(gt[0]), GCt = splat2(gt[1]);
    updp(sD, cD, cAd, sAd, GSd, GCd);
    updp(sT[0], cT[0], cAt, sAt, GSt, GCt);
    updp(sT[1], cT[1], cAt, sAt, GSt, GCt);
    REDUCE
    float Sd = (float)PD[0], Cd = (float)PD[1];
    float St = (float)PT[0], Ct = (float)PT[1];
    float ft = 1.f + 0.003f * Cd * __builtin_amdgcn_rsqf(Cd*Cd + Sd*Sd);
    float fg = 1.f + 0.003f * Ct * __builtin_amdgcn_rsqf(Ct*Ct + St*St);
    Pth *= ft; mPth = fminf(mPth, Pth);
    Pga *= fg; mPga = fminf(mPga, Pga);
  }
  #undef REDUCE

  const float cth = EPSV * Pth / mPth;
  const float cga = EPSV * Pga / mPga;
  {
    float4 a = *(const float4*)(amp + rb + 32 + 4*g);
    a.x = fmaxf(a.x*Pth, cth); a.y = fmaxf(a.y*Pth, cth);
    a.z = fmaxf(a.z*Pth, cth); a.w = fmaxf(a.w*Pth, cth);
    *(float4*)(amp + rb + 32 + 4*g) = a;
  }
  #pragma unroll
  for (int i = 0; i < 4; i++){
    float4 a = *(const float4*)(amp + rb + 96 + 16*g + 4*i);
    a.x = fmaxf(a.x*Pga, cga); a.y = fmaxf(a.y*Pga, cga);
    a.z = fmaxf(a.z*Pga, cga); a.w = fmaxf(a.w*Pga, cga);
    *(float4*)(amp + rb + 96 + 16*g + 4*i) = a;
  }
  // delta amps (factor 1): already final, written by gemm_k
}

// ---------------- launch ----------------
extern "C" void kernel_launch(void* const* d_in, const int* in_sizes, int n_in,
                              void* d_out, int out_size, void* d_ws, size_t ws_size,
                              hipStream_t stream){
  const float* x  = (const float*)d_in[0];
  const float* wp = (const float*)d_in[1];
  const float* wa = (const float*)d_in[2];
  float* out = (float*)d_out;
  char* ws = (char*)d_ws;
  u16* xb  = (u16*)(ws);                    // 8,388,608 B
  u16* wb  = (u16*)(ws + 8388608);          //   917,504 B (448 rows)
  u16* phase0 = (u16*)(ws + 9306112);       //   786,432 B (bf16, [4096][96])

  convert_k<<<4544, 256, 0, stream>>>((const f32x4*)x, (const f32x4*)wp, (const f32x4*)wa,
                                      (u16x4*)xb, (u16x4*)wb);
  gemm_k<<<896, 256, 0, stream>>>(xb, wb, phase0, out);
  iter_k<<<256, 256, 0, stream>>>(phase0, out);
}